// Round 8
// baseline (533.992 us; speedup 1.0000x reference)
//
#include <hip/hip_runtime.h>

// GCN 3-layer + mean pool, MI355X.
// R1: pool atomics -> segmented reduction (1106 -> 764us).
// R2: k_gemm rewrite 128x64 tile (confirmed R5: gemm left top-5).
// R5: k_agg2 latency-bound, VGPR=12, compiler serialized chains.
// R6 post-mortem: k_agg3 float2 lanes: 71 -> 65.5us only; VGPR=20 (still
//   ~2 chains); FETCH 188MB/agg (L2-miss path 2.9 TB/s), VALUBusy 31%.
//   Two hypotheses: latency (more chains => faster) vs L2-miss-path BW
//   ceiling (~3 TB/s => no change).
// R7: k_agg4 — 8 explicit chains, stage-grouped loads (8 colA -> 8 dis ->
//   8 rows -> FMA), masked tail. Decides H-lat vs H-bw.
//   (broker timeout; resubmitted unchanged — attribution discipline)

constexpr int KDIM = 128;   // inner dim of all three GEMMs
constexpr int NGRAPH = 64;

__global__ void k_init(int* __restrict__ counts, int n) {
  int i = blockIdx.x * blockDim.x + threadIdx.x;
  int stride = gridDim.x * blockDim.x;
  for (int j = i; j < n; j += stride) counts[j] = 0;
}

__global__ void k_hist(const int* __restrict__ src, const int* __restrict__ dst,
                       int* __restrict__ counts, int e, int n) {
  int i = blockIdx.x * blockDim.x + threadIdx.x;
  int stride = gridDim.x * blockDim.x;
  for (int j = i; j < e; j += stride) {
    int s = src[j], d = dst[j];
    if ((unsigned)s < (unsigned)n && (unsigned)d < (unsigned)n)
      atomicAdd(&counts[d], 1);
  }
}

__global__ void k_dis(const int* __restrict__ counts, float* __restrict__ dis, int n) {
  int i = blockIdx.x * blockDim.x + threadIdx.x;
  int stride = gridDim.x * blockDim.x;
  for (int j = i; j < n; j += stride)
    dis[j] = rsqrtf((float)counts[j] + 1.0f);
}

// per-block exclusive scan; blockSums[b] = block total
__global__ void k_scan_block(const int* __restrict__ in, int* __restrict__ outExcl,
                             int* __restrict__ blockSums, int n) {
  __shared__ int s[256];
  int tid = threadIdx.x;
  int i = blockIdx.x * 256 + tid;
  int v = (i < n) ? in[i] : 0;
  int x = v;
  s[tid] = x;
  __syncthreads();
  for (int off = 1; off < 256; off <<= 1) {
    int t = (tid >= off) ? s[tid - off] : 0;
    __syncthreads();
    x += t;
    s[tid] = x;
    __syncthreads();
  }
  if (i < n) outExcl[i] = x - v;
  if (tid == 255) blockSums[blockIdx.x] = x;
}

__global__ void k_scan_offsets(int* __restrict__ bs, int nb) {
  __shared__ int s[256];
  int tid = threadIdx.x;
  int v = (tid < nb) ? bs[tid] : 0;
  int x = v;
  s[tid] = x;
  __syncthreads();
  for (int off = 1; off < 256; off <<= 1) {
    int t = (tid >= off) ? s[tid - off] : 0;
    __syncthreads();
    x += t;
    s[tid] = x;
    __syncthreads();
  }
  if (tid < nb) bs[tid] = x - v;
  if (tid == nb - 1) bs[256] = x;  // total valid edges
}

__global__ void k_scan_add(int* __restrict__ row_start, const int* __restrict__ bs,
                           int* __restrict__ cursor, int n) {
  int i = blockIdx.x * blockDim.x + threadIdx.x;
  int stride = gridDim.x * blockDim.x;
  for (int j = i; j < n; j += stride) {
    int r = row_start[j] + bs[j >> 8];
    row_start[j] = r;
    cursor[j] = r;
  }
  if (i == 0) row_start[n] = bs[256];
}

__global__ void k_scatter(const int* __restrict__ src, const int* __restrict__ dst,
                          int* __restrict__ cursor, int* __restrict__ colA,
                          int e, int n) {
  int i = blockIdx.x * blockDim.x + threadIdx.x;
  int stride = gridDim.x * blockDim.x;
  for (int j = i; j < e; j += stride) {
    int s = src[j], d = dst[j];
    if ((unsigned)s < (unsigned)n && (unsigned)d < (unsigned)n) {
      int pos = atomicAdd(&cursor[d], 1);
      colA[pos] = s;
    }
  }
}

// H = X @ W.  Block tile 128 rows x 64 cols, BK=32. (unchanged from R2)
template <int DOUT>
__global__ __launch_bounds__(256) void k_gemm2(const float* __restrict__ X,
                                               const float* __restrict__ W,
                                               float* __restrict__ H, int n) {
  __shared__ float xT[32][128];  // 16 KB
  __shared__ float Wl[32][64];   // 8 KB
  const int tid = threadIdx.x;
  const int tr = tid & 15;
  const int tc = tid >> 4;
  const int rowBase = blockIdx.x * 128;
  const int colBase = blockIdx.y * 64;

  float acc[8][4];
#pragma unroll
  for (int i = 0; i < 8; ++i)
#pragma unroll
    for (int j = 0; j < 4; ++j) acc[i][j] = 0.f;

  const int sr = tid >> 1;
  const int kh = (tid & 1) * 16;
  const int srow = min(rowBase + sr, n - 1);
  const float* xsrc = X + (size_t)srow * KDIM + kh;

  for (int k0 = 0; k0 < KDIM / 32; ++k0) {
    {
      const float4* s4 = reinterpret_cast<const float4*>(xsrc + k0 * 32);
      float4 v0 = s4[0], v1 = s4[1], v2 = s4[2], v3 = s4[3];
      xT[kh + 0][sr] = v0.x;  xT[kh + 1][sr] = v0.y;
      xT[kh + 2][sr] = v0.z;  xT[kh + 3][sr] = v0.w;
      xT[kh + 4][sr] = v1.x;  xT[kh + 5][sr] = v1.y;
      xT[kh + 6][sr] = v1.z;  xT[kh + 7][sr] = v1.w;
      xT[kh + 8][sr] = v2.x;  xT[kh + 9][sr] = v2.y;
      xT[kh + 10][sr] = v2.z; xT[kh + 11][sr] = v2.w;
      xT[kh + 12][sr] = v3.x; xT[kh + 13][sr] = v3.y;
      xT[kh + 14][sr] = v3.z; xT[kh + 15][sr] = v3.w;
    }
#pragma unroll
    for (int q = 0; q < 2; ++q) {
      int f4 = tid + q * 256;
      int k = f4 >> 4;
      int c4 = f4 & 15;
      *reinterpret_cast<float4*>(&Wl[k][c4 * 4]) = *reinterpret_cast<const float4*>(
          W + (size_t)(k0 * 32 + k) * DOUT + colBase + c4 * 4);
    }
    __syncthreads();
#pragma unroll 8
    for (int k = 0; k < 32; ++k) {
      float4 xa = *reinterpret_cast<const float4*>(&xT[k][tr * 4]);
      float4 xb = *reinterpret_cast<const float4*>(&xT[k][64 + tr * 4]);
      float4 wv = *reinterpret_cast<const float4*>(&Wl[k][tc * 4]);
      const float xs[8] = {xa.x, xa.y, xa.z, xa.w, xb.x, xb.y, xb.z, xb.w};
      const float ws[4] = {wv.x, wv.y, wv.z, wv.w};
#pragma unroll
      for (int i = 0; i < 8; ++i)
#pragma unroll
        for (int j = 0; j < 4; ++j) acc[i][j] = fmaf(xs[i], ws[j], acc[i][j]);
    }
    __syncthreads();
  }

#pragma unroll
  for (int i = 0; i < 8; ++i) {
    int row = rowBase + ((i < 4) ? (tr * 4 + i) : (64 + tr * 4 + i - 4));
    if (row < n) {
      float4 o = {acc[i][0], acc[i][1], acc[i][2], acc[i][3]};
      *reinterpret_cast<float4*>(H + (size_t)row * DOUT + colBase + tc * 4) = o;
    }
  }
}

// R7 aggregation: 2 waves/node (even/odd edges). Per wave, batches of 8
// explicit gather chains with stage-grouped loads: 8x colA, then 8x dis,
// then 8x float2 row loads, then FMA. Masked tail via nrm=0 (H finite).
template <int D, bool RELU>
__global__ __launch_bounds__(256) void k_agg4(const float* __restrict__ H,
                                              const int* __restrict__ row_start,
                                              const int* __restrict__ colA,
                                              const float* __restrict__ dis,
                                              const float* __restrict__ bias,
                                              float* __restrict__ OUT, int n) {
  const int wave = threadIdx.x >> 6;
  const int lane = threadIdx.x & 63;
  const int slot = wave >> 1;
  const int half = wave & 1;
  const int node = blockIdx.x * 2 + slot;
  constexpr int C = D / 64;  // 2 (D=128) or 1 (D=64)
  __shared__ float red[4][D];

  if (node < n) {
    const int beg = row_start[node];
    const int end = row_start[node + 1];
    const float di = dis[node];
    float acc[C];
#pragma unroll
    for (int c = 0; c < C; ++c) acc[c] = 0.f;

    for (int base = beg + half; base < end; base += 16) {
      int s[8];
#pragma unroll
      for (int q = 0; q < 8; ++q) {
        const int ee = base + 2 * q;
        s[q] = (ee < end) ? colA[ee] : -1;
      }
      float nrm[8];
#pragma unroll
      for (int q = 0; q < 8; ++q) nrm[q] = (s[q] >= 0) ? dis[s[q]] * di : 0.f;
      if constexpr (C == 2) {
        float2 h[8];
#pragma unroll
        for (int q = 0; q < 8; ++q) {
          const int r = (s[q] >= 0) ? s[q] : 0;
          h[q] = *reinterpret_cast<const float2*>(H + (size_t)r * D + 2 * lane);
        }
#pragma unroll
        for (int q = 0; q < 8; ++q) {
          acc[0] = fmaf(h[q].x, nrm[q], acc[0]);
          acc[1] = fmaf(h[q].y, nrm[q], acc[1]);
        }
      } else {
        float h[8];
#pragma unroll
        for (int q = 0; q < 8; ++q) {
          const int r = (s[q] >= 0) ? s[q] : 0;
          h[q] = H[(size_t)r * D + lane];
        }
#pragma unroll
        for (int q = 0; q < 8; ++q) acc[0] = fmaf(h[q], nrm[q], acc[0]);
      }
    }
#pragma unroll
    for (int c = 0; c < C; ++c) red[wave][C * lane + c] = acc[c];
  } else {
#pragma unroll
    for (int c = 0; c < C; ++c) red[wave][C * lane + c] = 0.f;
  }
  __syncthreads();
  if (half == 0 && node < n) {
    const float di = dis[node];
    const float di2 = di * di;
    const float* hn = H + (size_t)node * D + C * lane;
    const float* bi = bias + C * lane;
    float* o = OUT + (size_t)node * D + C * lane;
#pragma unroll
    for (int c = 0; c < C; ++c) {
      float v = red[wave][C * lane + c] + red[wave + 1][C * lane + c] +
                hn[c] * di2 + bi[c];
      if (RELU) v = fmaxf(v, 0.f);
      o[c] = v;
    }
  }
}

// batch sorted -> one block per graph, binary-search range, no atomics.
__global__ __launch_bounds__(256) void k_pool2(const float* __restrict__ F,
                                               const int* __restrict__ batch,
                                               float* __restrict__ out, int n) {
  const int g = blockIdx.x;
  __shared__ int sb[2];
  if (threadIdx.x < 2) {
    int target = g + threadIdx.x;
    int lo = 0, hi = n;
    while (lo < hi) {
      int mid = (lo + hi) >> 1;
      if (batch[mid] < target) lo = mid + 1; else hi = mid;
    }
    sb[threadIdx.x] = lo;
  }
  __syncthreads();
  const int beg = sb[0], end = sb[1];
  const int wave = threadIdx.x >> 6;
  const int lane = threadIdx.x & 63;
  float acc = 0.f;
  for (int node = beg + wave; node < end; node += 4)
    acc += F[(size_t)node * 64 + lane];
  __shared__ float red[4][64];
  red[wave][lane] = acc;
  __syncthreads();
  if (wave == 0) {
    float v = (red[0][lane] + red[1][lane]) + (red[2][lane] + red[3][lane]);
    out[g * 64 + lane] = v / fmaxf((float)(end - beg), 1.f);
  }
}

extern "C" void kernel_launch(void* const* d_in, const int* in_sizes, int n_in,
                              void* d_out, int out_size, void* d_ws, size_t ws_size,
                              hipStream_t stream) {
  const float* x     = (const float*)d_in[0];
  const int*   ei    = (const int*)d_in[1];
  const int*   batch = (const int*)d_in[2];
  const float* W1 = (const float*)d_in[3];
  const float* b1 = (const float*)d_in[4];
  const float* W2 = (const float*)d_in[5];
  const float* b2 = (const float*)d_in[6];
  const float* W3 = (const float*)d_in[7];
  const float* b3 = (const float*)d_in[8];

  const int n = in_sizes[0] / KDIM;   // 50000
  const int e = in_sizes[1] / 2;      // 800000
  const int* src = ei;
  const int* dst = ei + e;

  char* p = (char*)d_ws;
  size_t off = 0;
  auto carve = [&](size_t bytes) {
    char* r = p + off;
    off = (off + bytes + 255) & ~(size_t)255;
    return r;
  };
  float* bufA      = (float*)carve((size_t)n * KDIM * 4);
  float* bufB      = (float*)carve((size_t)n * KDIM * 4);
  float* dis       = (float*)carve((size_t)n * 4);
  int*   counts    = (int*)carve((size_t)n * 4);
  int*   row_start = (int*)carve((size_t)(n + 1) * 4);
  int*   cursor    = (int*)carve((size_t)n * 4);
  int*   colA      = (int*)carve((size_t)e * 4);
  int*   blockSums = (int*)carve(512 * 4);
  (void)ws_size;

  const int nb1 = (n + 255) / 256;
  const int GS = 1024;

  k_init<<<GS, 256, 0, stream>>>(counts, n);
  k_hist<<<GS, 256, 0, stream>>>(src, dst, counts, e, n);
  k_dis<<<nb1, 256, 0, stream>>>(counts, dis, n);
  k_scan_block<<<nb1, 256, 0, stream>>>(counts, row_start, blockSums, n);
  k_scan_offsets<<<1, 256, 0, stream>>>(blockSums, nb1);
  k_scan_add<<<nb1, 256, 0, stream>>>(row_start, blockSums, cursor, n);
  k_scatter<<<GS, 256, 0, stream>>>(src, dst, cursor, colA, e, n);

  const int rowBlocks = (n + 127) / 128;  // 391
  const int aggGrid = (n + 1) / 2;        // 2 nodes per block

  // layer 1
  k_gemm2<128><<<dim3(rowBlocks, 2), 256, 0, stream>>>(x, W1, bufA, n);
  k_agg4<128, true><<<aggGrid, 256, 0, stream>>>(bufA, row_start, colA, dis, b1, bufB, n);
  // layer 2
  k_gemm2<128><<<dim3(rowBlocks, 2), 256, 0, stream>>>(bufB, W2, bufA, n);
  k_agg4<128, true><<<aggGrid, 256, 0, stream>>>(bufA, row_start, colA, dis, b2, bufB, n);
  // layer 3
  k_gemm2<64><<<dim3(rowBlocks, 1), 256, 0, stream>>>(bufB, W3, bufA, n);
  k_agg4<64, false><<<aggGrid, 256, 0, stream>>>(bufA, row_start, colA, dis, b3,
                                                 (float*)d_out, n);
  // pooling
  k_pool2<<<NGRAPH, 256, 0, stream>>>((const float*)d_out, batch,
                                      (float*)d_out + (size_t)n * 64, n);
}